// Round 1
// baseline (103.548 us; speedup 1.0000x reference)
//
#include <hip/hip_runtime.h>
#include <math.h>

#define NN   512
#define BB   16
#define EMB  32
#define HID  64
#define TILE 64
#define LDSP 68   // padded LDS row stride in dwords (272 B, 16B-aligned, breaks bank conflicts)

// ---------------------------------------------------------------------------
// Kernel A: per-node factorization of the first layer.
//   u[n][h] = sum_e H[n][e] * W1[e][h]      + b1[h]   (h_i half, bias folded)
//   v[n][h] = sum_e H[n][e] * W1[e+32][h]              (h_j half)
// ---------------------------------------------------------------------------
__global__ __launch_bounds__(256) void precompute_uv(
    const float* __restrict__ emb, const float* __restrict__ W1,
    const float* __restrict__ b1, float* __restrict__ u, float* __restrict__ v)
{
    int g = blockIdx.x * 256 + threadIdx.x;   // 0 .. 8192*64-1
    int n = g >> 6, h = g & 63;
    const float* Hrow = emb + n * EMB;
    float su = b1[h];
    float sv = 0.f;
    #pragma unroll
    for (int e = 0; e < EMB; ++e) {
        float he = Hrow[e];                       // wave-uniform (n uniform per wave), L1 broadcast
        su = fmaf(he, W1[e * HID + h], su);       // coalesced across h-lanes
        sv = fmaf(he, W1[(e + EMB) * HID + h], sv);
    }
    u[n * HID + h] = su;
    v[n * HID + h] = sv;
}

// ---------------------------------------------------------------------------
// Kernel B: 64x64 output tile per block (upper-triangle tiles only).
// Element (R,C), R<C uses prob = sigmoid(W2 . relu(u[R] + v[C]) + b2).
// Off-diagonal block (bi<bj): every element has R<C -> uniform fast path;
// writes tile (bi,bj) from registers and tile (bj,bi) via LDS transpose.
// Diagonal block: computes all, writes with per-element min/max, zero diag.
// ---------------------------------------------------------------------------
__global__ __launch_bounds__(256) void edge_tile(
    const float* __restrict__ u, const float* __restrict__ v,
    const float* __restrict__ W2, const float* __restrict__ b2p,
    float* __restrict__ out)
{
    int bj = blockIdx.x, bi = blockIdx.y, b = blockIdx.z;
    if (bi > bj) return;   // whole block exits; no syncthreads hazard

    __shared__ __align__(16) float u_s[TILE][LDSP];
    __shared__ __align__(16) float v_s[TILE][LDSP];

    int t = threadIdx.x;

    // ---- stage u (rows = smaller index range bi) and v (rows = bj range) ----
    const float* ubase = u + ((size_t)b * NN + bi * TILE) * HID;
    const float* vbase = v + ((size_t)b * NN + bj * TILE) * HID;
    {
        int row  = t >> 4;          // 0..15
        int col  = (t & 15) * 4;    // 0..60
        #pragma unroll
        for (int p = 0; p < 4; ++p) {
            int rr = row + p * 16;
            *(float4*)&u_s[rr][col] = *(const float4*)&ubase[rr * HID + col];
            *(float4*)&v_s[rr][col] = *(const float4*)&vbase[rr * HID + col];
        }
    }
    __syncthreads();

    // ---- compute 4x4 micro-tile, strided mapping r=tr+16i, c=tc+16j ----
    int tr = t >> 4;   // 0..15
    int tc = t & 15;   // 0..15

    float acc[4][4];
    #pragma unroll
    for (int i = 0; i < 4; ++i)
        #pragma unroll
        for (int j = 0; j < 4; ++j) acc[i][j] = 0.f;

    const float4* w2v = (const float4*)W2;
    #pragma unroll 4
    for (int h4 = 0; h4 < 16; ++h4) {
        float4 a[4], bv[4];
        #pragma unroll
        for (int k = 0; k < 4; ++k) a[k]  = *(const float4*)&u_s[tr + 16*k][h4 * 4];
        #pragma unroll
        for (int k = 0; k < 4; ++k) bv[k] = *(const float4*)&v_s[tc + 16*k][h4 * 4];
        float4 w = w2v[h4];   // uniform -> scalar loads
        #pragma unroll
        for (int i = 0; i < 4; ++i)
            #pragma unroll
            for (int j = 0; j < 4; ++j) {
                float x0 = fmaxf(a[i].x + bv[j].x, 0.f);
                float x1 = fmaxf(a[i].y + bv[j].y, 0.f);
                float x2 = fmaxf(a[i].z + bv[j].z, 0.f);
                float x3 = fmaxf(a[i].w + bv[j].w, 0.f);
                acc[i][j] = fmaf(x0, w.x, acc[i][j]);
                acc[i][j] = fmaf(x1, w.y, acc[i][j]);
                acc[i][j] = fmaf(x2, w.z, acc[i][j]);
                acc[i][j] = fmaf(x3, w.w, acc[i][j]);
            }
    }

    float b2 = b2p[0];
    float val[4][4];
    #pragma unroll
    for (int i = 0; i < 4; ++i)
        #pragma unroll
        for (int j = 0; j < 4; ++j) {
            float x = acc[i][j] + b2;
            val[i][j] = 1.f / (1.f + __expf(-x));
        }

    float* res = &u_s[0][0];   // reuse u_s as [64][LDSP] result buffer after sync

    if (bi != bj) {
        // write own tile (bi,bj) straight from registers (coalesced across tc lanes)
        float* obase = out + (size_t)b * NN * NN + (size_t)(bi * TILE) * NN + bj * TILE;
        #pragma unroll
        for (int i = 0; i < 4; ++i) {
            int r = tr + 16 * i;
            #pragma unroll
            for (int j = 0; j < 4; ++j)
                obase[r * NN + tc + 16 * j] = val[i][j];
        }
        __syncthreads();   // everyone done reading u_s
        #pragma unroll
        for (int i = 0; i < 4; ++i)
            #pragma unroll
            for (int j = 0; j < 4; ++j)
                res[(tc + 16 * j) * LDSP + (tr + 16 * i)] = val[i][j];  // transposed
        __syncthreads();
        // write mirror tile (bj,bi), coalesced float4 rows
        float* obase2 = out + (size_t)b * NN * NN + (size_t)(bj * TILE) * NN + bi * TILE;
        int row  = t >> 2;          // 0..63
        int col0 = (t & 3) * 16;    // 0,16,32,48
        #pragma unroll
        for (int q = 0; q < 4; ++q)
            *(float4*)&obase2[row * NN + col0 + q * 4] =
                *(const float4*)&res[row * LDSP + col0 + q * 4];
    } else {
        // diagonal tile: stash all values, then emit with min/max indexing
        __syncthreads();
        #pragma unroll
        for (int i = 0; i < 4; ++i)
            #pragma unroll
            for (int j = 0; j < 4; ++j)
                res[(tr + 16 * i) * LDSP + (tc + 16 * j)] = val[i][j];
        __syncthreads();
        float* obase = out + (size_t)b * NN * NN + (size_t)(bi * TILE) * NN + bj * TILE;
        int row  = t >> 2;          // 0..63
        int col0 = (t & 3) * 16;
        for (int q = 0; q < 16; ++q) {
            int c = col0 + q;
            float x;
            if (row == c)      x = 0.f;
            else if (row < c)  x = res[row * LDSP + c];   // valid upper value
            else               x = res[c * LDSP + row];   // mirror of upper value
            obase[row * NN + c] = x;
        }
    }
}

extern "C" void kernel_launch(void* const* d_in, const int* in_sizes, int n_in,
                              void* d_out, int out_size, void* d_ws, size_t ws_size,
                              hipStream_t stream) {
    const float* emb = (const float*)d_in[0];   // (8192, 32)
    const float* W1  = (const float*)d_in[1];   // (64, 64)
    const float* b1  = (const float*)d_in[2];   // (64,)
    const float* W2  = (const float*)d_in[3];   // (64, 1)
    const float* b2  = (const float*)d_in[4];   // (1,)
    // d_in[5], d_in[6] are B, N scalars; shapes are fixed -> compiled in.
    float* outp = (float*)d_out;                // (16, 512, 512)

    float* uu = (float*)d_ws;                          // 8192*64 floats (2 MB)
    float* vv = uu + (size_t)BB * NN * HID;            // 8192*64 floats (2 MB)

    precompute_uv<<<dim3((BB * NN * HID) / 256), 256, 0, stream>>>(emb, W1, b1, uu, vv);

    dim3 grid(NN / TILE, NN / TILE, BB);
    edge_tile<<<grid, 256, 0, stream>>>(uu, vv, W2, b2, outp);
}

// Round 2
// 96.541 us; speedup vs baseline: 1.0726x; 1.0726x over previous
//
#include <hip/hip_runtime.h>
#include <math.h>

#define NN   512
#define BB   16
#define EMB  32
#define HID  64
#define TILE 64
#define ROWD 36    // dwords per LDS row: 32 data (64 halves) + 4 pad (breaks bank alignment)
#define RST  68    // fp32 result-staging row stride in dwords

typedef _Float16 h2 __attribute__((ext_vector_type(2)));

// ---------------------------------------------------------------------------
// Kernel A: per-node factorization of layer 1 (fp32 math, f16 output).
//   u[n][h] = sum_e H[n][e]*W1[e][h] + b1[h]   ;   v[n][h] = sum_e H[n][e]*W1[e+32][h]
// ---------------------------------------------------------------------------
__global__ __launch_bounds__(256) void precompute_uv(
    const float* __restrict__ emb, const float* __restrict__ W1,
    const float* __restrict__ b1, _Float16* __restrict__ u, _Float16* __restrict__ v)
{
    int g = blockIdx.x * 256 + threadIdx.x;   // 0 .. 8192*64-1
    int n = g >> 6, h = g & 63;
    const float* Hrow = emb + n * EMB;
    float su = b1[h];
    float sv = 0.f;
    #pragma unroll
    for (int e = 0; e < EMB; ++e) {
        float he = Hrow[e];                       // wave-uniform, L1 broadcast
        su = fmaf(he, W1[e * HID + h], su);       // coalesced across h-lanes
        sv = fmaf(he, W1[(e + EMB) * HID + h], sv);
    }
    u[n * HID + h] = (_Float16)su;
    v[n * HID + h] = (_Float16)sv;
}

// ---------------------------------------------------------------------------
// Kernel B: 64x64 tile per block, upper-triangle tiles only.
// prob(R,C) = sigmoid(W2 . relu(u[R]+v[C]) + b2), R<C.
// f16 packed math: pk_add + pk_max + dot2(f32 acc). Both output tiles written
// as fully coalesced 256B rows via LDS staging.
// ---------------------------------------------------------------------------
__global__ __launch_bounds__(256) void edge_tile(
    const _Float16* __restrict__ u, const _Float16* __restrict__ v,
    const float* __restrict__ W2, const float* __restrict__ b2p,
    float* __restrict__ out)
{
    int bj = blockIdx.x, bi = blockIdx.y, b = blockIdx.z;
    if (bi > bj) return;

    __shared__ __align__(16) float smem[2 * TILE * ROWD];   // u_s | v_s, later reused as res
    __shared__ float w2s[HID / 2];                           // W2 packed to half2 bit patterns
    float* u_s = smem;                  // [64][ROWD] dwords, 32 data dwords/row
    float* v_s = smem + TILE * ROWD;
    float* res = smem;                  // [64][RST] fp32 result staging (after sync)

    int t = threadIdx.x;

    // ---- stage u (rows in bi range) and v (rows in bj range) as halves ----
    const _Float16* ubase = u + ((size_t)b * NN + bi * TILE) * HID;
    const _Float16* vbase = v + ((size_t)b * NN + bj * TILE) * HID;
    {
        // 64 rows x 8 float4 (16B = 8 halves) = 512 vec4 loads, 2 per thread
        #pragma unroll
        for (int p = 0; p < 2; ++p) {
            int idx = t + p * 256;          // 0..511
            int row = idx >> 3, c4 = idx & 7;
            *(float4*)&u_s[row * ROWD + c4 * 4] = *(const float4*)&ubase[row * HID + c4 * 8];
            *(float4*)&v_s[row * ROWD + c4 * 4] = *(const float4*)&vbase[row * HID + c4 * 8];
        }
        if (t < 32) {
            float2 w = ((const float2*)W2)[t];
            h2 hw = { (_Float16)w.x, (_Float16)w.y };
            w2s[t] = __builtin_bit_cast(float, hw);
        }
    }
    __syncthreads();

    // ---- preload packed W2 into registers ----
    float4 w2f[8];
    #pragma unroll
    for (int q = 0; q < 8; ++q) w2f[q] = *(const float4*)&w2s[q * 4];

    int tr = t >> 4;   // 0..15  row strip
    int tc = t & 15;   // 0..15  col strip

    float acc[4][4];
    #pragma unroll
    for (int i = 0; i < 4; ++i)
        #pragma unroll
        for (int j = 0; j < 4; ++j) acc[i][j] = 0.f;

    const h2 hz = { (_Float16)0.f, (_Float16)0.f };

    #pragma unroll
    for (int h8 = 0; h8 < 8; ++h8) {            // 8 halves per iteration
        float4 a[4], bv[4];
        #pragma unroll
        for (int k = 0; k < 4; ++k) a[k]  = *(const float4*)&u_s[(tr + 16 * k) * ROWD + h8 * 4];
        #pragma unroll
        for (int k = 0; k < 4; ++k) bv[k] = *(const float4*)&v_s[(tc + 16 * k) * ROWD + h8 * 4];
        float4 w = w2f[h8];
        h2 w0 = __builtin_bit_cast(h2, w.x), w1 = __builtin_bit_cast(h2, w.y);
        h2 w2_ = __builtin_bit_cast(h2, w.z), w3 = __builtin_bit_cast(h2, w.w);
        #pragma unroll
        for (int i = 0; i < 4; ++i) {
            h2 ax = __builtin_bit_cast(h2, a[i].x), ay = __builtin_bit_cast(h2, a[i].y);
            h2 az = __builtin_bit_cast(h2, a[i].z), aw = __builtin_bit_cast(h2, a[i].w);
            #pragma unroll
            for (int j = 0; j < 4; ++j) {
                h2 bx = __builtin_bit_cast(h2, bv[j].x), by = __builtin_bit_cast(h2, bv[j].y);
                h2 bz = __builtin_bit_cast(h2, bv[j].z), bw = __builtin_bit_cast(h2, bv[j].w);
                float s = acc[i][j];
                s = __builtin_amdgcn_fdot2(__builtin_elementwise_max(ax + bx, hz), w0, s, false);
                s = __builtin_amdgcn_fdot2(__builtin_elementwise_max(ay + by, hz), w1, s, false);
                s = __builtin_amdgcn_fdot2(__builtin_elementwise_max(az + bz, hz), w2_, s, false);
                s = __builtin_amdgcn_fdot2(__builtin_elementwise_max(aw + bw, hz), w3, s, false);
                acc[i][j] = s;
            }
        }
    }

    float b2 = b2p[0];
    float val[4][4];
    #pragma unroll
    for (int i = 0; i < 4; ++i)
        #pragma unroll
        for (int j = 0; j < 4; ++j) {
            float x = acc[i][j] + b2;
            val[i][j] = 1.f / (1.f + __expf(-x));
        }

    __syncthreads();   // everyone done reading u_s/v_s; smem becomes res

    int r16 = t >> 4;          // 0..15
    int l16 = t & 15;          // 0..15

    if (bi != bj) {
        // ---- tile (bi,bj): stage direct, write 256B-contiguous rows ----
        #pragma unroll
        for (int i = 0; i < 4; ++i)
            #pragma unroll
            for (int j = 0; j < 4; ++j)
                res[(tr + 16 * i) * RST + tc + 16 * j] = val[i][j];
        __syncthreads();
        float* o1 = out + (size_t)b * NN * NN + (size_t)(bi * TILE) * NN + bj * TILE;
        #pragma unroll
        for (int q = 0; q < 4; ++q) {
            int r = r16 + q * 16;
            *(float4*)&o1[(size_t)r * NN + l16 * 4] = *(const float4*)&res[r * RST + l16 * 4];
        }
        __syncthreads();
        // ---- tile (bj,bi): stage transposed, write rows ----
        #pragma unroll
        for (int i = 0; i < 4; ++i)
            #pragma unroll
            for (int j = 0; j < 4; ++j)
                res[(tc + 16 * j) * RST + tr + 16 * i] = val[i][j];
        __syncthreads();
        float* o2 = out + (size_t)b * NN * NN + (size_t)(bj * TILE) * NN + bi * TILE;
        #pragma unroll
        for (int q = 0; q < 4; ++q) {
            int r = r16 + q * 16;
            *(float4*)&o2[(size_t)r * NN + l16 * 4] = *(const float4*)&res[r * RST + l16 * 4];
        }
    } else {
        // ---- diagonal tile: stage all, emit with min/max indexing + zero diag ----
        #pragma unroll
        for (int i = 0; i < 4; ++i)
            #pragma unroll
            for (int j = 0; j < 4; ++j)
                res[(tr + 16 * i) * RST + tc + 16 * j] = val[i][j];
        __syncthreads();
        float* obase = out + (size_t)b * NN * NN + (size_t)(bi * TILE) * NN + bj * TILE;
        int row  = t >> 2;          // 0..63
        int col0 = (t & 3) * 16;
        for (int q = 0; q < 16; ++q) {
            int c = col0 + q;
            float x;
            if (row == c)      x = 0.f;
            else if (row < c)  x = res[row * RST + c];
            else               x = res[c * RST + row];
            obase[(size_t)row * NN + c] = x;
        }
    }
}

extern "C" void kernel_launch(void* const* d_in, const int* in_sizes, int n_in,
                              void* d_out, int out_size, void* d_ws, size_t ws_size,
                              hipStream_t stream) {
    const float* emb = (const float*)d_in[0];   // (8192, 32)
    const float* W1  = (const float*)d_in[1];   // (64, 64)
    const float* b1  = (const float*)d_in[2];   // (64,)
    const float* W2  = (const float*)d_in[3];   // (64, 1)
    const float* b2  = (const float*)d_in[4];   // (1,)
    float* outp = (float*)d_out;                // (16, 512, 512) fp32

    _Float16* uu = (_Float16*)d_ws;                    // 8192*64 halves (1 MB)
    _Float16* vv = uu + (size_t)BB * NN * HID;         // 8192*64 halves (1 MB)

    precompute_uv<<<dim3((BB * NN * HID) / 256), 256, 0, stream>>>(emb, W1, b1, uu, vv);

    dim3 grid(NN / TILE, NN / TILE, BB);
    edge_tile<<<grid, 256, 0, stream>>>(uu, vv, W2, b2, outp);
}